// Round 17
// baseline (547.679 us; speedup 1.0000x reference)
//
#include <hip/hip_runtime.h>

typedef __attribute__((ext_vector_type(8))) short bf16x8;
typedef __attribute__((ext_vector_type(4))) float f32x4;
typedef __attribute__((ext_vector_type(4))) unsigned short us4;
typedef __attribute__((ext_vector_type(8))) unsigned short us8;

#define NROWS 262144
#define KC 256
#define DD 256
#define BM 64        // rows per tile; block = 8 tiles = 512 rows
#define NTILE 8
#define GRID 512     // all blocks co-resident (2/CU)
#define TAU 1.5e-3f
#define FCAP 65536
#define ZSW 264      // z LDS row stride in halves

// ===== bit-exact numpy emulation helpers (defeat -ffp-contract) =====
__device__ __forceinline__ float np_pw128_sq(const float* a) {
    float r[8];
#pragma unroll
    for (int j = 0; j < 8; ++j) r[j] = __fmul_rn(a[j], a[j]);
    for (int i = 8; i < 128; i += 8) {
#pragma unroll
        for (int j = 0; j < 8; ++j)
            r[j] = __fadd_rn(r[j], __fmul_rn(a[i + j], a[i + j]));
    }
    float t01 = __fadd_rn(r[0], r[1]), t23 = __fadd_rn(r[2], r[3]);
    float t45 = __fadd_rn(r[4], r[5]), t67 = __fadd_rn(r[6], r[7]);
    return __fadd_rn(__fadd_rn(t01, t23), __fadd_rn(t45, t67));
}
__device__ __forceinline__ float np_sum256_sq(const float* a) {
    return __fadd_rn(np_pw128_sq(a), np_pw128_sq(a + 128));
}
__device__ __forceinline__ unsigned short bf16_rne(float x) {
    unsigned b = __float_as_uint(x);
    b += 0x7FFFu + ((b >> 16) & 1u);
    return (unsigned short)(b >> 16);
}

// ---------- prep ----------
__global__ void vq_prep(const float* __restrict__ emb, float* __restrict__ se,
                        double* __restrict__ accum, int* __restrict__ gcnt) {
    int k = threadIdx.x;
    if (k == 0) { *accum = 0.0; *gcnt = 0; }
    se[k] = np_sum256_sq(emb + (size_t)k * DD);
}

// ---------- split emb -> FRAG-LINEAR bf16 plane (r16 layout) ----------
__global__ void vq_split(const float* __restrict__ emb, unsigned short* __restrict__ ph) {
    int f = (blockIdx.x * 256 + threadIdx.x) * 4;
    float4 v = *reinterpret_cast<const float4*>(emb + f);
    int k = f >> 8, d = f & 255;
    int off = (d >> 5) * 8192 + (k >> 4) * 512 + (k & 15) * 32 + ((d >> 3) & 3) * 8 + (d & 7);
    us4 h;
    h[0] = bf16_rne(v.x); h[1] = bf16_rne(v.y);
    h[2] = bf16_rne(v.z); h[3] = bf16_rne(v.w);
    *reinterpret_cast<us4*>(ph + off) = h;
}

// ========== ABLATION PROBE A0: z-stream only (identical shape to vq_main staging) ==========
__global__ __launch_bounds__(256, 2)
void vq_a0(const float* __restrict__ ze, float* __restrict__ sink) {
    __shared__ float red[256];
    const int t = threadIdx.x;
    float sz = 0.f;
    for (int tile = 0; tile < NTILE; ++tile) {
        const size_t m0 = (size_t)blockIdx.x * (BM * NTILE) + tile * BM;
        float4 zr[16];
#pragma unroll
        for (int it = 0; it < 16; ++it) {
            int idx = it * 256 + t;
            int row = idx >> 6, c4 = idx & 63;
            zr[it] = *reinterpret_cast<const float4*>(ze + (m0 + row) * DD + c4 * 4);
        }
#pragma unroll
        for (int it = 0; it < 16; ++it) {
            float4 v = zr[it];
            sz = fmaf(v.x, v.x, sz); sz = fmaf(v.y, v.y, sz);
            sz = fmaf(v.z, v.z, sz); sz = fmaf(v.w, v.w, sz);
        }
    }
    red[t] = sz;
    __syncthreads();
    for (int s = 128; s > 0; s >>= 1) { if (t < s) red[t] += red[t + s]; __syncthreads(); }
    if (t == 0) sink[blockIdx.x] = red[0];
}

// ========== ABLATION PROBE A3: e-dbuf copy + barrier pipeline only (same LDS/occupancy) ==========
__global__ __launch_bounds__(256, 2)
void vq_a3(const unsigned short* __restrict__ ph, float* __restrict__ sink) {
    __shared__ __attribute__((aligned(16))) unsigned short eb[2][8192];
    __shared__ unsigned short pad[19000];   // match vq_main's ~72KB LDS footprint
    __shared__ float red[256];
    const int t = threadIdx.x;
    const int w = t >> 6, q = (t >> 4) & 3, c = t & 15;
    float acc = 0.f;
    us8 er[4];
    for (int tile = 0; tile < NTILE; ++tile) {
#pragma unroll
        for (int i = 0; i < 4; ++i)
            er[i] = *reinterpret_cast<const us8*>(ph + (i * 256 + t) * 8);
#pragma unroll
        for (int i = 0; i < 4; ++i)
            *reinterpret_cast<us8*>(&eb[0][(i * 256 + t) * 8]) = er[i];
        __syncthreads();
#pragma unroll
        for (int dci = 0; dci < 8; ++dci) {
            const int cur = dci & 1;
            if (dci < 7) {
                const unsigned short* src = ph + (dci + 1) * 8192;
#pragma unroll
                for (int i = 0; i < 4; ++i)
                    er[i] = *reinterpret_cast<const us8*>(src + (i * 256 + t) * 8);
            }
#pragma unroll
            for (int nf = 0; nf < 4; ++nf) {
                us8 a = *reinterpret_cast<const us8*>(&eb[cur][((4 * w + nf) * 64 + c * 4 + q) * 8]);
                acc += (float)a[0] + (float)a[7];
            }
            if (dci < 7) {
#pragma unroll
                for (int i = 0; i < 4; ++i)
                    *reinterpret_cast<us8*>(&eb[cur ^ 1][(i * 256 + t) * 8]) = er[i];
            }
            __syncthreads();
        }
    }
    pad[t] = (unsigned short)acc;
    __syncthreads();
    red[t] = acc + (float)pad[255 - t];
    __syncthreads();
    for (int s = 128; s > 0; s >>= 1) { if (t < s) red[t] += red[t + s]; __syncthreads(); }
    if (t == 0) sink[GRID + blockIdx.x] = red[0];
}

// ---------- main v17: 8 tiles/block, cross-tile z reg-prefetch, r16 inner structure ----------
__global__ __launch_bounds__(256, 2)
void vq_main(const float* __restrict__ ze, const unsigned short* __restrict__ ph,
             const float* __restrict__ se_g, float* __restrict__ out_inds,
             double* __restrict__ accum, int* __restrict__ glist, int* __restrict__ gcnt)
{
    __shared__ __attribute__((aligned(16))) unsigned short zl[BM * ZSW];
    __shared__ __attribute__((aligned(16))) unsigned short eb[2][8192];
    __shared__ float se_s[KC];
    __shared__ float wv1[4 * BM], wv2[4 * BM];
    __shared__ int   wk1[4 * BM];
    __shared__ float red[256];

    const int t = threadIdx.x;
    const int w = t >> 6;
    const int q = (t >> 4) & 3;
    const int c = t & 15;
    const size_t b0 = (size_t)blockIdx.x * (BM * NTILE);

    se_s[t] = se_g[t];

    float sz_acc = 0.f, lossv = 0.f;

    // prologue: z loads for tile 0
    float4 zr[16];
#pragma unroll
    for (int it = 0; it < 16; ++it) {
        int idx = it * 256 + t;
        int row = idx >> 6, c4 = idx & 63;
        zr[it] = *reinterpret_cast<const float4*>(ze + (b0 + row) * DD + c4 * 4);
    }

    for (int tile = 0; tile < NTILE; ++tile) {
        const size_t m0 = b0 + tile * BM;
        // ---- cvt staged z regs -> LDS (+ sz) ----
#pragma unroll
        for (int it = 0; it < 16; ++it) {
            float4 v = zr[it];
            int idx = it * 256 + t;
            int row = idx >> 6, c4 = idx & 63;
            sz_acc = fmaf(v.x, v.x, sz_acc); sz_acc = fmaf(v.y, v.y, sz_acc);
            sz_acc = fmaf(v.z, v.z, sz_acc); sz_acc = fmaf(v.w, v.w, sz_acc);
            us4 h;
            h[0] = bf16_rne(v.x); h[1] = bf16_rne(v.y);
            h[2] = bf16_rne(v.z); h[3] = bf16_rne(v.w);
            *reinterpret_cast<us4*>(&zl[row * ZSW + c4 * 4]) = h;
        }
        // ---- issue NEXT tile's z loads (in flight across this tile's K-loop) ----
        if (tile < NTILE - 1) {
            const size_t m1 = m0 + BM;
#pragma unroll
            for (int it = 0; it < 16; ++it) {
                int idx = it * 256 + t;
                int row = idx >> 6, c4 = idx & 63;
                zr[it] = *reinterpret_cast<const float4*>(ze + (m1 + row) * DD + c4 * 4);
            }
        }
        // ---- stage e chunk 0 ----
        us8 er[4];
#pragma unroll
        for (int i = 0; i < 4; ++i)
            er[i] = *reinterpret_cast<const us8*>(ph + (i * 256 + t) * 8);
#pragma unroll
        for (int i = 0; i < 4; ++i)
            *reinterpret_cast<us8*>(&eb[0][(i * 256 + t) * 8]) = er[i];
        __syncthreads();

        f32x4 acc[4][4];
#pragma unroll
        for (int i = 0; i < 4; ++i)
#pragma unroll
            for (int j = 0; j < 4; ++j) acc[i][j] = (f32x4){0.f, 0.f, 0.f, 0.f};

        // ---- K-loop: 8 chunks, one barrier each ----
#pragma unroll
        for (int dci = 0; dci < 8; ++dci) {
            const int cur = dci & 1;
            if (dci < 7) {
                const unsigned short* src = ph + (dci + 1) * 8192;
#pragma unroll
                for (int i = 0; i < 4; ++i)
                    er[i] = *reinterpret_cast<const us8*>(src + (i * 256 + t) * 8);
            }
            bf16x8 af[4];
#pragma unroll
            for (int mf = 0; mf < 4; ++mf)
                af[mf] = *reinterpret_cast<const bf16x8*>(&zl[(16 * mf + c) * ZSW + dci * 32 + q * 8]);
#pragma unroll
            for (int nf = 0; nf < 4; ++nf) {
                bf16x8 bf = *reinterpret_cast<const bf16x8*>(&eb[cur][((4 * w + nf) * 64 + c * 4 + q) * 8]);
#pragma unroll
                for (int mf = 0; mf < 4; ++mf)
                    acc[mf][nf] = __builtin_amdgcn_mfma_f32_16x16x32_bf16(af[mf], bf, acc[mf][nf], 0, 0, 0);
            }
            if (dci < 7) {
#pragma unroll
                for (int i = 0; i < 4; ++i)
                    *reinterpret_cast<us8*>(&eb[cur ^ 1][(i * 256 + t) * 8]) = er[i];
            }
            __syncthreads();
        }

        // ---- per-row argmin over this wave's 64-code slice ----
#pragma unroll
        for (int mf = 0; mf < 4; ++mf)
#pragma unroll
            for (int j = 0; j < 4; ++j) {
                float v1 = 3.4e38f, v2 = 3.4e38f; int k1 = 0x7fffffff;
#pragma unroll
                for (int nf = 0; nf < 4; ++nf) {
                    int k = 64 * w + 16 * nf + c;
                    float dv = fmaf(-2.f, acc[mf][nf][j], se_s[k]);
                    if (dv < v1) { v2 = v1; v1 = dv; k1 = k; }
                    else if (dv < v2) { v2 = dv; }
                }
#pragma unroll
                for (int off = 1; off < 16; off <<= 1) {
                    float ov1 = __shfl_xor(v1, off, 64);
                    float ov2 = __shfl_xor(v2, off, 64);
                    int   ok1 = __shfl_xor(k1, off, 64);
                    bool other = (ov1 < v1) || (ov1 == v1 && ok1 < k1);
                    float nv2 = other ? fminf(v1, ov2) : fminf(v2, ov1);
                    if (other) { v1 = ov1; k1 = ok1; }
                    v2 = nv2;
                }
                if (c == 0) {
                    int row = 16 * mf + 4 * q + j;
                    wv1[w * BM + row] = v1; wv2[w * BM + row] = v2; wk1[w * BM + row] = k1;
                }
            }
        __syncthreads();

        // ---- cross-wave merge, write inds, flag ----
        if (t < BM) {
            float v1 = wv1[t], v2 = wv2[t]; int k1 = wk1[t];
#pragma unroll
            for (int ww = 1; ww < 4; ++ww) {
                float ov1 = wv1[ww * BM + t], ov2 = wv2[ww * BM + t];
                int ok1 = wk1[ww * BM + t];
                bool other = (ov1 < v1) || (ov1 == v1 && ok1 < k1);
                float nv2 = other ? fminf(v1, ov2) : fminf(v2, ov1);
                if (other) { v1 = ov1; k1 = ok1; }
                v2 = nv2;
            }
            out_inds[m0 + t] = (float)k1;
            lossv += v1;
            if (v2 - v1 < TAU) {
                int s_ = atomicAdd(gcnt, 1);
                if (s_ < FCAP) glist[s_] = (int)(m0 + t);
            }
        }
        __syncthreads();
    }

    // ---- loss partial (once per block) ----
    red[t] = sz_acc + (t < BM ? lossv : 0.f);
    __syncthreads();
    for (int s = 128; s > 0; s >>= 1) {
        if (t < s) red[t] += red[t + s];
        __syncthreads();
    }
    if (t == 0) atomicAdd(accum, (double)red[0]);
}

// ---------- deferred fix (r13-proven) ----------
__global__ __launch_bounds__(256)
void vq_fix(const float* __restrict__ ze, const float* __restrict__ emb,
            const float* __restrict__ se_g, const int* __restrict__ glist,
            const int* __restrict__ gcnt, float* __restrict__ out_inds)
{
    __shared__ float dq[16][256];
    __shared__ float srow_s[16];
    __shared__ int   rowid_s[16];

    const int t = threadIdx.x;
    int F = *gcnt; if (F > FCAP) F = FCAP;
    const float se_k = se_g[t];
    const float4* e4p = reinterpret_cast<const float4*>(emb + (size_t)t * DD);

    for (int g = blockIdx.x * 16; g < F; g += gridDim.x * 16) {
        __syncthreads();
        if (t < 16) {
            int idx = g + t; if (idx > F - 1) idx = F - 1;
            int row = glist[idx];
            rowid_s[t] = row;
            srow_s[t] = np_sum256_sq(ze + (size_t)row * DD);
        }
        __syncthreads();

        const float* zp[16];
#pragma unroll
        for (int r = 0; r < 16; ++r)
            zp[r] = ze + (size_t)__builtin_amdgcn_readfirstlane(rowid_s[r]) * DD;

        float m32[16];
#pragma unroll
        for (int r = 0; r < 16; ++r) m32[r] = 0.f;
        for (int d4 = 0; d4 < 64; ++d4) {
            float4 e4 = e4p[d4];
            const int d = d4 * 4;
#pragma unroll
            for (int r = 0; r < 16; ++r) {
                m32[r] = __fmaf_rn(zp[r][d + 0], e4.x, m32[r]);
                m32[r] = __fmaf_rn(zp[r][d + 1], e4.y, m32[r]);
                m32[r] = __fmaf_rn(zp[r][d + 2], e4.z, m32[r]);
                m32[r] = __fmaf_rn(zp[r][d + 3], e4.w, m32[r]);
            }
        }
#pragma unroll
        for (int r = 0; r < 16; ++r) {
            float A = __fadd_rn(srow_s[r], se_k);
            dq[r][t] = __fsub_rn(A, __fmul_rn(2.0f, m32[r]));
        }
        __syncthreads();

        {
            const int r = t >> 4, p = t & 15;
            float bv = 3.4e38f; int bk = 0x7fffffff;
#pragma unroll
            for (int i = 0; i < 16; ++i) {
                int k = p * 16 + i;
                float v = dq[r][k];
                if (v < bv) { bv = v; bk = k; }
            }
#pragma unroll
            for (int off = 1; off < 16; off <<= 1) {
                float ov = __shfl_xor(bv, off, 64);
                int   ok = __shfl_xor(bk, off, 64);
                if (ov < bv || (ov == bv && ok < bk)) { bv = ov; bk = ok; }
            }
            if (p == 0 && g + r < F) out_inds[rowid_s[r]] = (float)bk;
        }
        __syncthreads();
    }
}

// ---------- gather ----------
__global__ __launch_bounds__(256)
void vq_gather(const float* __restrict__ emb, const float* __restrict__ out_inds,
               float* __restrict__ out_zq)
{
    const int t = threadIdx.x;
    const int w = t >> 6, l = t & 63;
    const size_t m0 = (size_t)blockIdx.x * 128 + (size_t)w * 32;
#pragma unroll 8
    for (int r = 0; r < 32; ++r) {
        int k = (int)out_inds[m0 + r];
        float4 v = *reinterpret_cast<const float4*>(emb + (size_t)k * DD + l * 4);
        *reinterpret_cast<float4*>(out_zq + (m0 + r) * DD + l * 4) = v;
    }
}

// ---------- finalize ----------
__global__ void vq_fin(const double* __restrict__ accum, float* __restrict__ out_loss) {
    *out_loss = (float)(1.25 * (*accum) / ((double)NROWS * (double)DD));
}

extern "C" void kernel_launch(void* const* d_in, const int* in_sizes, int n_in,
                              void* d_out, int out_size, void* d_ws, size_t ws_size,
                              hipStream_t stream) {
    const float* ze  = (const float*)d_in[0];
    const float* emb = (const float*)d_in[1];
    float* out      = (float*)d_out;
    float* out_zq   = out;
    float* out_inds = out + (size_t)NROWS * DD;
    float* out_loss = out + (size_t)NROWS * DD + NROWS;

    double* accum = (double*)d_ws;                                        // @0
    int*    gcnt  = (int*)((char*)d_ws + 8);                              // @8
    float*  se    = (float*)((char*)d_ws + 256);                          // @256
    int*    glist = (int*)((char*)d_ws + 4096);                           // @4K, 256KB
    unsigned short* ph = (unsigned short*)((char*)d_ws + 4096 + 262144);  // 128KB
    float*  sink  = (float*)((char*)d_ws + 4096 + 262144 + 131072);       // 8KB probe sink

    vq_prep<<<1, 256, 0, stream>>>(emb, se, accum, gcnt);
    vq_split<<<KC * DD / (256 * 4), 256, 0, stream>>>(emb, ph);
    vq_a0<<<GRID, 256, 0, stream>>>(ze, sink);          // ablation: z-stream only
    vq_a3<<<GRID, 256, 0, stream>>>(ph, sink);          // ablation: e+barrier pipeline only
    vq_main<<<GRID, 256, 0, stream>>>(ze, ph, se, out_inds, accum, glist, gcnt);
    vq_fix<<<1024, 256, 0, stream>>>(ze, emb, se, glist, gcnt, out_inds);
    vq_gather<<<NROWS / 128, 256, 0, stream>>>(emb, out_inds, out_zq);
    vq_fin<<<1, 1, 0, stream>>>(accum, out_loss);
}